// Round 13
// baseline (464.127 us; speedup 1.0000x reference)
//
#include <hip/hip_runtime.h>
#include <hip/hip_bf16.h>
#include <math.h>

typedef __bf16 bf16x8 __attribute__((ext_vector_type(8)));
typedef __bf16 bf16x4 __attribute__((ext_vector_type(4)));
typedef float  f32x4  __attribute__((ext_vector_type(4)));

#define S_LEN 2048
#define NB    8
#define NH    16
#define NP    8
#define DIM   1024

struct F8 { float v[8]; };

__device__ __forceinline__ void gld16(const void* g, void* l) {
  __builtin_amdgcn_global_load_lds(
      (__attribute__((address_space(1))) void*)g,
      (__attribute__((address_space(3))) void*)l, 16, 0, 0);
}

// ---------------- prep kernels ----------------

__global__ void k_cast2(const float* __restrict__ x, __bf16* __restrict__ xb,
                        const float* __restrict__ wt, __bf16* __restrict__ wt1b) {
  int i = blockIdx.x * 256 + threadIdx.x;
  const float* src; __bf16* dst;
  if (i < 4194304) { src = x; dst = xb; }
  else { i -= 4194304; if (i >= 262144) return; src = wt; dst = wt1b; }
  float4 v = reinterpret_cast<const float4*>(src)[i];
  bf16x4 o;
  o.x = (__bf16)v.x; o.y = (__bf16)v.y; o.z = (__bf16)v.z; o.w = (__bf16)v.w;
  reinterpret_cast<bf16x4*>(dst)[i] = o;
}

__global__ __launch_bounds__(256) void k_pack_all(
    const float* __restrict__ Wq, const float* __restrict__ Wk, const float* __restrict__ Wv,
    const float* __restrict__ Wo, const float* __restrict__ Woff, const float* __restrict__ Wps,
    __bf16* __restrict__ wcat, __bf16* __restrict__ wot, __bf16* __restrict__ w2t) {
  const int y = blockIdx.y;
  const float* W; __bf16* dst; int N = 1024;
  switch (y) {
    case 0: W = Wq;   dst = wcat;            break;
    case 1: W = Wk;   dst = wcat + 1048576;  break;
    case 2: W = Wv;   dst = wcat + 2097152;  break;
    case 3: W = Wo;   dst = wot;             break;
    case 4: W = Woff; dst = w2t;            N = 128; break;
    default: W = Wps; dst = w2t + 131072;   N = 128; break;
  }
  const int K = 1024;
  const int ntn = N >> 6;
  const int nblk = (K >> 6) * ntn;
  if (blockIdx.x >= nblk) return;
  __shared__ float t[64][65];
  const int bk = blockIdx.x / ntn, bn = blockIdx.x - bk * ntn;
  const int tid = threadIdx.x;
  const int c4 = tid & 15;
  const int r0 = tid >> 4;
#pragma unroll
  for (int rp = 0; rp < 4; ++rp) {
    const int row = rp * 16 + r0;
    float4 v = *(const float4*)(W + (size_t)(bk * 64 + row) * N + bn * 64 + c4 * 4);
    t[row][c4 * 4 + 0] = v.x; t[row][c4 * 4 + 1] = v.y;
    t[row][c4 * 4 + 2] = v.z; t[row][c4 * 4 + 3] = v.w;
  }
  __syncthreads();
  const int n = tid >> 2, q = tid & 3;
  bf16x8 o0, o1;
#pragma unroll
  for (int j = 0; j < 8; ++j) o0[j] = (__bf16)t[q * 16 + j][n];
#pragma unroll
  for (int j = 0; j < 8; ++j) o1[j] = (__bf16)t[q * 16 + 8 + j][n];
  __bf16* dp = dst + (size_t)(bn * 64 + n) * K + bk * 64 + q * 16;
  *(bf16x8*)dp = o0;
  *(bf16x8*)(dp + 8) = o1;
}

// parallel prep A: wc_t/biasp (y=0) and ebt rows (y=1..9); 4-way K-split, LDS reduce
__global__ __launch_bounds__(256) void k_prepA(
    const float* __restrict__ Wc, const float* __restrict__ bc,
    const float* __restrict__ Eb, const float* __restrict__ Wt,
    const float* __restrict__ bt,
    float* __restrict__ wc_t, float* __restrict__ biasp, float* __restrict__ ebt) {
  __shared__ float red[2][4][64];
  const int chunk = blockIdx.x;
  const int y = blockIdx.y;
  const int dl_ = threadIdx.x & 63, kp = threadIdx.x >> 6;
  const int d = chunk * 64 + dl_;
  float a0 = 0.f, a1 = 0.f;
  if (y == 0) {
    for (int f = kp * 64; f < kp * 64 + 64; ++f) {
      float wv = Wt[(size_t)(1024 + f) * 1024 + d];
      a0 += Wc[f] * wv;
      a1 += bc[f] * wv;
    }
  } else {
    const float* e = Eb + (y - 1) * 256;
    for (int f = kp * 64; f < kp * 64 + 64; ++f)
      a0 += e[f] * Wt[(size_t)(1280 + f) * 1024 + d];
  }
  red[0][kp][dl_] = a0;
  red[1][kp][dl_] = a1;
  __syncthreads();
  if (kp == 0) {
    float s0 = red[0][0][dl_] + red[0][1][dl_] + red[0][2][dl_] + red[0][3][dl_];
    if (y == 0) {
      float s1 = red[1][0][dl_] + red[1][1][dl_] + red[1][2][dl_] + red[1][3][dl_];
      wc_t[d] = s0;
      biasp[d] = bt[d] + s1;
    } else {
      ebt[(y - 1) * 1024 + d] = s0;
    }
  }
}

// parallel prep B: cw2 (v=0), bo2 (v=1), ebo rows (v=2..10); 8-way K-split
__global__ __launch_bounds__(512) void k_prepB(
    const float* __restrict__ wc_t, const float* __restrict__ biasp,
    const float* __restrict__ ebt,
    const float* __restrict__ Woff, const float* __restrict__ Wps,
    const float* __restrict__ boff, const float* __restrict__ bps,
    float* __restrict__ cw2, float* __restrict__ bo2, float* __restrict__ ebo) {
  __shared__ float red[8][64];
  const int chunk = blockIdx.x;
  const int v = blockIdx.y;
  const int jl = threadIdx.x & 63, kp = threadIdx.x >> 6;
  const int j = chunk * 64 + jl;
  const float* vec = (v == 0) ? wc_t : (v == 1) ? biasp : ebt + (v - 2) * 1024;
  const float* W2 = (j < 128) ? (Woff + j) : (Wps + j - 128);
  float a = 0.f;
  for (int d = kp * 128; d < kp * 128 + 128; ++d)
    a += vec[d] * W2[(size_t)d * 128];
  red[kp][jl] = a;
  __syncthreads();
  if (kp == 0) {
    float s = 0.f;
#pragma unroll
    for (int q = 0; q < 8; ++q) s += red[q][jl];
    if (v == 0)      cw2[j] = s;
    else if (v == 1) bo2[j] = s + ((j < 128) ? boff[j] : bps[j - 128]);
    else             ebo[(v - 2) * 256 + j] = s;
  }
}

// prep C: ebias concat (blocks 0-11) + dec/pbias (block 12)
__global__ void k_prepC(const float* __restrict__ bq, const float* __restrict__ bk,
                        const float* __restrict__ bv,
                        const float* __restrict__ tdw, const float* __restrict__ tdb,
                        const float* __restrict__ point_bias,
                        float* __restrict__ ebias, float* __restrict__ dec,
                        float* __restrict__ pbias) {
  const int blk = blockIdx.x, tid = threadIdx.x;
  if (blk < 12) {
    const int i = blk * 256 + tid;
    const float* src = (i < 1024) ? bq : (i < 2048) ? bk : bv;
    ebias[i] = src[i & 1023];
  } else if (tid < 128) {
    dec[tid] = log1pf(expf(tdw[tid]));
    pbias[tid] = tdb[tid] + point_bias[tid];
  }
}

__global__ void k_rowcum(const float* __restrict__ td, float* __restrict__ dl,
                         int* __restrict__ bucket, float* __restrict__ el) {
  __shared__ float part[256];
  __shared__ float pre[256];
  const int b = blockIdx.x, t = threadIdx.x;
  const float* x = td + b * S_LEN;
  float* o = el + b * S_LEN;
  const float B0[8] = {0.f, 0.5f, 1.f, 2.f, 4.f, 8.f, 12.f, 24.f};
  float loc[8];
  float run = 0.f;
#pragma unroll
  for (int j = 0; j < 8; ++j) {
    const int i = t * 8 + j;
    float dt = fmaxf(x[i], 0.f);
    dl[b * S_LEN + i] = log1pf(dt);
    int bk = 0;
#pragma unroll
    for (int q = 0; q < 8; ++q) bk += (B0[q] < dt) ? 1 : 0;
    bucket[b * S_LEN + i] = bk;
    run += dt; loc[j] = run;
  }
  part[t] = run;
  __syncthreads();
  if (t == 0) {
    float acc = 0.f;
    for (int i = 0; i < 256; ++i) { pre[i] = acc; acc += part[i]; }
  }
  __syncthreads();
  float base = pre[t];
#pragma unroll
  for (int j = 0; j < 8; ++j) o[t * 8 + j] = base + loc[j];
}

// ---------------- GEMM params ----------------

struct GP {
  const __bf16* A; const __bf16* Bt;
  int M, N, K;
  __bf16 *qb, *kb, *vb;
  const float *ebias, *cw2, *ebo, *bo2, *dl;
  const int* bucket;
  float *offa, *psa;
  float* outp; const float* bo;
};

// ---------------- G1: 128x128, BK=32, 4 waves, TRIPLE buffer, prefetch distance 2 -------
// 48KB LDS -> 3 blocks/CU (12 waves); tile-t loads issued 2 steps (~800+ cyc) before
// their vmcnt wait -> HBM latency covered. vmcnt(16): wait oldest 8 (tile t), keep
// t+1/t+2's 16 in flight. Race-free: buf[(t+2)%3] last read step t-1, ordered by its
// trailing barrier. Staging/read swizzle = R9-verified BK=32 scheme.

template <int MODE>
__global__ __launch_bounds__(256) void k_g128c(GP pr) {
  __shared__ __align__(16) __bf16 As[3][128 * 32];
  __shared__ __align__(16) __bf16 Bs[3][128 * 32];
  const int tid = threadIdx.x;
  const int wave = tid >> 6, lane = tid & 63;
  const int wm = wave >> 1, wn = wave & 1;      // 2 x 2 wave grid, wave tile 64(M) x 64(N)
  const int rA = lane & 15, rG = lane >> 4;

  const int nwg = gridDim.x;
  const int cpx = nwg >> 3;
  const int wg = (blockIdx.x & 7) * cpx + (blockIdx.x >> 3);

  const int nbn = pr.N >> 7;
  const int bm = wg / nbn, bn = wg - bm * nbn;
  const int m0 = bm << 7, n0 = bn << 7;
  const int K = pr.K;
  const int NT = K >> 5;

  const int srow = wave * 16 + (lane >> 2);
  const int scs = ((lane & 3) ^ ((lane >> 3) & 3)) << 3;
  const int ldso = wave * 1024;

  const __bf16* Ar0 = pr.A  + (size_t)(m0 + srow) * K;
  const __bf16* Ar1 = pr.A  + (size_t)(m0 + 64 + srow) * K;
  const __bf16* Br0 = pr.Bt + (size_t)(n0 + srow) * K;
  const __bf16* Br1 = pr.Bt + (size_t)(n0 + 64 + srow) * K;

#define STG128(tt, bi) do {                                  \
    const int c_ = ((tt) << 5) + scs;                        \
    gld16(Ar0 + c_, (char*)As[bi] + ldso);                   \
    gld16(Ar1 + c_, (char*)As[bi] + 4096 + ldso);            \
    gld16(Br0 + c_, (char*)Bs[bi] + ldso);                   \
    gld16(Br1 + c_, (char*)Bs[bi] + 4096 + ldso);            \
  } while (0)

  f32x4 acc[4][4] = {};

  const int slot = (rG ^ ((rA >> 1) & 3)) << 4;
  const int aoff = wm * 4096 + rA * 64 + slot;
  const int boff = wn * 4096 + rA * 64 + slot;

  STG128(0, 0);
  STG128(1, 1);

  int b0 = 0, b1 = 1, b2 = 2;
  for (int t = 0; t < NT; ++t) {
    if (t + 2 < NT) {
      STG128(t + 2, b2);
      asm volatile("s_waitcnt vmcnt(16)" ::: "memory");
    } else if (t + 1 < NT) {
      asm volatile("s_waitcnt vmcnt(8)" ::: "memory");
    } else {
      asm volatile("s_waitcnt vmcnt(0)" ::: "memory");
    }
    __builtin_amdgcn_s_barrier();
    asm volatile("" ::: "memory");

    bf16x8 af[4], bfv[4];
#pragma unroll
    for (int mt = 0; mt < 4; ++mt)
      af[mt] = *(const bf16x8*)((const char*)As[b0] + aoff + mt * 1024);
#pragma unroll
    for (int nt = 0; nt < 4; ++nt)
      bfv[nt] = *(const bf16x8*)((const char*)Bs[b0] + boff + nt * 1024);
    __builtin_amdgcn_s_setprio(1);
#pragma unroll
    for (int mt = 0; mt < 4; ++mt)
#pragma unroll
      for (int nt = 0; nt < 4; ++nt)
        acc[mt][nt] = __builtin_amdgcn_mfma_f32_16x16x32_bf16(bfv[nt], af[mt], acc[mt][nt], 0, 0, 0);
    __builtin_amdgcn_s_setprio(0);

    asm volatile("" ::: "memory");
    __builtin_amdgcn_s_barrier();
    const int tmp = b0; b0 = b1; b1 = b2; b2 = tmp;
  }
#undef STG128

  // epilogue: acc = C^T frag; lane owns row gr, 4 consecutive cols per nt
#pragma unroll
  for (int mt = 0; mt < 4; ++mt) {
    const int gr = m0 + wm * 64 + mt * 16 + rA;
    if constexpr (MODE == 0) {
      const int seg = n0 >> 10;
      if (seg < 3) {
        __bf16* dst = (seg == 0) ? pr.qb : (seg == 1) ? pr.kb : pr.vb;
        const int dbase = n0 & 1023;
        __bf16* rowp = dst + (size_t)gr * 1024;
#pragma unroll
        for (int nt = 0; nt < 4; ++nt) {
          const int d0 = dbase + wn * 64 + nt * 16 + rG * 4;
          bf16x4 o;
#pragma unroll
          for (int i = 0; i < 4; ++i)
            o[i] = (__bf16)(acc[mt][nt][i] + pr.ebias[(seg << 10) + d0 + i]);
          *(bf16x4*)(rowp + d0) = o;
        }
      } else {
        const float dlv = pr.dl[gr];
        const int bkt = pr.bucket[gr];
        const int bb = gr >> 11, ss = gr & 2047;
#pragma unroll
        for (int nt = 0; nt < 4; ++nt) {
          const int j0 = (n0 & 1023) + wn * 64 + nt * 16 + rG * 4;
#pragma unroll
          for (int i = 0; i < 4; ++i) {
            const int j = j0 + i;
            float v = acc[mt][nt][i] + dlv * pr.cw2[j] + pr.ebo[bkt * 256 + j] + pr.bo2[j];
            if (j < 128) {
              const int hh = j >> 3, pp = j & 7;
              pr.offa[(((size_t)bb * NH + hh) * S_LEN + ss) * NP + pp] = tanhf(v);
            } else {
              const int jj = j - 128, hh = jj >> 3, pp = jj & 7;
              pr.psa[(((size_t)bb * NH + hh) * S_LEN + ss) * NP + pp] = v;
            }
          }
        }
      }
    } else {
      float* rowp = pr.outp + (size_t)gr * 1024;
#pragma unroll
      for (int nt = 0; nt < 4; ++nt) {
        const int d0 = n0 + wn * 64 + nt * 16 + rG * 4;
        f32x4 o;
#pragma unroll
        for (int i = 0; i < 4; ++i) o[i] = acc[mt][nt][i] + pr.bo[d0 + i];
        *(f32x4*)(rowp + d0) = o;
      }
    }
  }
}

// ---------------- G3: 256x256, BK=64, 8 waves, counted vmcnt (R8-proven) ---------------

template <int MODE>
__global__ __launch_bounds__(512, 2) void k_gemm2(GP pr) {
  __shared__ __align__(16) __bf16 As[2][256 * 64];
  __shared__ __align__(16) __bf16 Bs[2][256 * 64];
  const int tid = threadIdx.x;
  const int wave = tid >> 6, lane = tid & 63;
  const int wm = wave >> 2, wn = wave & 3;
  const int rA = lane & 15, rG = lane >> 4;

  const int nwg = gridDim.x;
  const int cpx = nwg >> 3;
  const int wg = (blockIdx.x & 7) * cpx + (blockIdx.x >> 3);

  const int nbn = pr.N >> 8;
  const int bm = wg / nbn, bn = wg - bm * nbn;
  const int m0 = bm << 8, n0 = bn << 8;
  const int K = pr.K;
  const int NT = K >> 6;

  const int srow = wave * 8 + (lane >> 3);
  const int sslot = lane & 7;

  f32x4 acc[8][4] = {};

#pragma unroll
  for (int r = 0; r < 4; ++r) {
    const int row = r * 64 + srow;
    const int fb = r * 8192 + wave * 1024;
    const int col = (sslot ^ (row & 7)) << 3;
    gld16(pr.A  + (size_t)(m0 + row) * K + col, (char*)As[0] + fb);
    gld16(pr.Bt + (size_t)(n0 + row) * K + col, (char*)Bs[0] + fb);
  }

  int buf = 0;
  for (int t = 0; t < NT; ++t) {
    if (t + 1 < NT) {
      const int k0 = (t + 1) << 6;
#pragma unroll
      for (int r = 0; r < 4; ++r) {
        const int row = r * 64 + srow;
        const int fb = r * 8192 + wave * 1024;
        const int col = k0 + ((sslot ^ (row & 7)) << 3);
        gld16(pr.A  + (size_t)(m0 + row) * K + col, (char*)As[buf ^ 1] + fb);
        gld16(pr.Bt + (size_t)(n0 + row) * K + col, (char*)Bs[buf ^ 1] + fb);
      }
      asm volatile("s_waitcnt vmcnt(8)" ::: "memory");
    } else {
      asm volatile("s_waitcnt vmcnt(0)" ::: "memory");
    }
    __builtin_amdgcn_s_barrier();
    asm volatile("" ::: "memory");

#pragma unroll
    for (int kk = 0; kk < 2; ++kk) {
      bf16x8 af[8], bfv[4];
#pragma unroll
      for (int mt = 0; mt < 8; ++mt) {
        const int row = wm * 128 + mt * 16 + rA;
        const int slot = ((kk * 4 + rG) ^ (row & 7)) << 4;
        af[mt] = *(const bf16x8*)((const char*)As[buf] + row * 128 + slot);
      }
#pragma unroll
      for (int nt = 0; nt < 4; ++nt) {
        const int row = wn * 64 + nt * 16 + rA;
        const int slot = ((kk * 4 + rG) ^ (row & 7)) << 4;
        bfv[nt] = *(const bf16x8*)((const char*)Bs[buf] + row * 128 + slot);
      }
      __builtin_amdgcn_s_setprio(1);
#pragma unroll
      for (int mt = 0; mt < 8; ++mt)
#pragma unroll
        for (int nt = 0; nt < 4; ++nt)
          acc[mt][nt] = __builtin_amdgcn_mfma_f32_16x16x32_bf16(bfv[nt], af[mt], acc[mt][nt], 0, 0, 0);
      __builtin_amdgcn_s_setprio(0);
    }
    asm volatile("" ::: "memory");
    __builtin_amdgcn_s_barrier();
    buf ^= 1;
  }

#pragma unroll
  for (int mt = 0; mt < 8; ++mt) {
    const int gr = m0 + wm * 128 + mt * 16 + rA;
    float* rowp = pr.outp + (size_t)gr * 1024;
#pragma unroll
    for (int nt = 0; nt < 4; ++nt) {
      const int d0 = n0 + wn * 64 + nt * 16 + rG * 4;
      f32x4 o;
#pragma unroll
      for (int i = 0; i < 4; ++i) o[i] = acc[mt][nt][i] + pr.bo[d0 + i];
      *(f32x4*)(rowp + d0) = o;
    }
  }
}

// ---------------- 128x128 m97-style GEMM: combined-weight prep ----------------

__global__ __launch_bounds__(256) void k_wcomb(GP pr) {
  __shared__ __bf16 As[128 * 32];
  __shared__ __bf16 Bs[128 * 32];
  const int tid = threadIdx.x;
  const int wave = tid >> 6, lane = tid & 63;
  const int wm = wave >> 1, wn = wave & 1;
  const int nbn = pr.N >> 7;
  const int bm = blockIdx.x / nbn, bn = blockIdx.x - bm * nbn;
  const int m0 = bm << 7, n0 = bn << 7;
  const int K = pr.K;
  const int rA = lane & 15, rG = lane >> 4;

  f32x4 acc[4][4] = {};

  for (int k0 = 0; k0 < K; k0 += 32) {
#pragma unroll
    for (int ch = 0; ch < 2; ++ch) {
      const int fb = ch * 4096 + wave * 1024;
      const int e = (fb >> 1) + lane * 8;
      const int row = e >> 5, col = e & 31;
      gld16(pr.A  + (size_t)(m0 + row) * K + (k0 + col), (char*)As + fb);
      gld16(pr.Bt + (size_t)(n0 + row) * K + (k0 + col), (char*)Bs + fb);
    }
    __syncthreads();

    bf16x8 af[4], bfv[4];
#pragma unroll
    for (int mt = 0; mt < 4; ++mt)
      af[mt] = *(const bf16x8*)&As[(wm * 64 + mt * 16 + rA) * 32 + rG * 8];
#pragma unroll
    for (int nt = 0; nt < 4; ++nt)
      bfv[nt] = *(const bf16x8*)&Bs[(wn * 64 + nt * 16 + rA) * 32 + rG * 8];
#pragma unroll
    for (int mt = 0; mt < 4; ++mt)
#pragma unroll
      for (int nt = 0; nt < 4; ++nt)
        acc[mt][nt] = __builtin_amdgcn_mfma_f32_16x16x32_bf16(af[mt], bfv[nt], acc[mt][nt], 0, 0, 0);
    __syncthreads();
  }

#pragma unroll
  for (int mt = 0; mt < 4; ++mt) {
#pragma unroll
    for (int nt = 0; nt < 4; ++nt) {
      const int gc = n0 + wn * 64 + nt * 16 + rA;
      const int grb = m0 + wm * 64 + mt * 16 + rG * 4;
#pragma unroll
      for (int i = 0; i < 4; ++i)
        pr.qb[(size_t)(grb + i) * 1024 + gc] = (__bf16)acc[mt][nt][i];
    }
  }
}

// ---------------- deformable attention v7: NO LDS — K/V/elapsed via L1/L2 --------------
// K-window (34KB) ~ L1 size; staging + barriers were overhead (guide m169 pattern).
// Zero LDS -> 5 blocks/CU (20 waves). XCD-chunk swizzle keeps (b,h) K/V on one L2.

__global__ __launch_bounds__(256) void k_attn7(
    const __bf16* __restrict__ qb, const __bf16* __restrict__ kb, const __bf16* __restrict__ vb,
    const float* __restrict__ offa, const float* __restrict__ psa,
    const float* __restrict__ elapsed,
    const float* __restrict__ dec, const float* __restrict__ pbias,
    __bf16* __restrict__ attn_out, F8 anchors) {
  const int nwg = gridDim.x;              // 2048
  const int cpx = nwg >> 3;
  const int wg = (blockIdx.x & 7) * cpx + (blockIdx.x >> 3);
  const int t0 = wg & 15, h = (wg >> 4) & 15, b = wg >> 8;
  const int s0 = t0 * 128;
  const int tid = threadIdx.x;
  const size_t bBase = (size_t)b * S_LEN;
  const int hd0 = h * 64;

  const int wv = tid >> 6, lane = tid & 63;
  const int p = lane & 7, c = lane >> 3;
  const int pb0 = p & 1, pb1 = (p >> 1) & 1, pb2 = p >> 2;
  const float anchor = anchors.v[p];
  const int hp = h * NP + p;
  const float decv = dec[hp], pbv = pbias[hp];

  const int sw0 = s0 + wv * 32;
  const __bf16* kbase = kb + bBase * DIM + hd0 + c * 8;
  const __bf16* vbase = vb + bBase * DIM + hd0 + c * 8;
  const __bf16* qbase = qb + bBase * DIM + hd0 + c * 8;
  const float* elb = elapsed + b * S_LEN;
  size_t ppos0 = (((size_t)b * NH + h) * S_LEN + sw0) * NP + p;

#pragma unroll 2
  for (int i = 0; i < 32; ++i) {
    const int s = sw0 + i;
    const float off = offa[ppos0 + (size_t)i * NP];
    const float psv = psa[ppos0 + (size_t)i * NP];
    const bf16x8 qv = *(const bf16x8*)(qbase + (size_t)s * DIM);

    float pos = (float)s - anchor + off * 8.0f;
    pos = fminf(fmaxf(pos, 0.0f), (float)s);
    int li = (int)pos;
    const float alpha = pos - (float)li;
    int ri = li + 1; if (ri > S_LEN - 1) ri = S_LEN - 1;

    const bf16x8 kl = *(const bf16x8*)(kbase + (size_t)li * DIM);
    const bf16x8 kr = *(const bf16x8*)(kbase + (size_t)ri * DIM);
    const bf16x8 vl = *(const bf16x8*)(vbase + (size_t)li * DIM);
    const bf16x8 vr = *(const bf16x8*)(vbase + (size_t)ri * DIM);

    float dpl = 0.f, dpr = 0.f;
#pragma unroll
    for (int j = 0; j < 8; ++j) {
      dpl += (float)qv[j] * (float)kl[j];
      dpr += (float)qv[j] * (float)kr[j];
    }
    float dot = dpl + alpha * (dpr - dpl);
    dot += __shfl_xor(dot, 8);    // reduce over c
    dot += __shfl_xor(dot, 16);
    dot += __shfl_xor(dot, 32);

    const float el_s = elb[s];
    const float ell = elb[li];
    const float elr2 = elb[ri];
    const float elsamp = ell + alpha * (elr2 - ell);
    const float rel = log1pf(fmaxf(el_s - elsamp, 0.f));
    const float score = dot * 0.125f + psv + pbv - decv * rel;

    const float e = expf(score);
    float dsum = e;                // reduce over p
    dsum += __shfl_xor(dsum, 1);
    dsum += __shfl_xor(dsum, 2);
    dsum += __shfl_xor(dsum, 4);
    const float wgt = e / dsum;
    const float wl = wgt * (1.0f - alpha), wr = wgt * alpha;

    float o[8];
#pragma unroll
    for (int j = 0; j < 8; ++j)
      o[j] = wl * (float)vl[j] + wr * (float)vr[j];

    // butterfly over p (masks 1/2/4): lane (c,p) ends with channel c*8+p
    float r00 = (pb0 ? o[1] : o[0]) + __shfl_xor(pb0 ? o[0] : o[1], 1);
    float r01 = (pb0 ? o[3] : o[2]) + __shfl_xor(pb0 ? o[2] : o[3], 1);
    float r02 = (pb0 ? o[5] : o[4]) + __shfl_xor(pb0 ? o[4] : o[5], 1);
    float r03 = (pb0 ? o[7] : o[6]) + __shfl_xor(pb0 ? o[6] : o[7], 1);
    float r10 = (pb1 ? r01 : r00) + __shfl_xor(pb1 ? r00 : r01, 2);
    float r11 = (pb1 ? r03 : r02) + __shfl_xor(pb1 ? r02 : r03, 2);
    float rf = (pb2 ? r11 : r10) + __shfl_xor(pb2 ? r10 : r11, 4);

    attn_out[(bBase + s) * DIM + hd0 + c * 8 + p] = (__bf16)rf;
  }
}

// ---------------- host ----------------

extern "C" void kernel_launch(void* const* d_in, const int* in_sizes, int n_in,
                              void* d_out, int out_size, void* d_ws, size_t ws_size,
                              hipStream_t stream) {
  const float* x    = (const float*)d_in[0];
  const float* td   = (const float*)d_in[1];
  const float* Wq   = (const float*)d_in[2];
  const float* bq   = (const float*)d_in[3];
  const float* Wk   = (const float*)d_in[4];
  const float* bk   = (const float*)d_in[5];
  const float* Wv   = (const float*)d_in[6];
  const float* bv   = (const float*)d_in[7];
  const float* Wc   = (const float*)d_in[8];
  const float* bc   = (const float*)d_in[9];
  const float* Eb   = (const float*)d_in[10];
  const float* Wt   = (const float*)d_in[11];
  const float* bt   = (const float*)d_in[12];
  const float* Woff = (const float*)d_in[13];
  const float* boff = (const float*)d_in[14];
  const float* Wps  = (const float*)d_in[15];
  const float* bps  = (const float*)d_in[16];
  const float* Wo   = (const float*)d_in[17];
  const float* bo   = (const float*)d_in[18];
  const float* pb   = (const float*)d_in[19];
  const float* tdw  = (const float*)d_in[20];
  const float* tdb  = (const float*)d_in[21];

  char* w = (char*)d_ws;
  size_t off = 0;
  auto take = [&](size_t n) {
    char* pp = w + off;
    off += (n + 255) & ~(size_t)255;
    return pp;
  };
  __bf16* xb    = (__bf16*)take(33554432);
  __bf16* wcat  = (__bf16*)take(8388608);
  __bf16* w2t   = (__bf16*)take(524288);
  __bf16* wot   = (__bf16*)take(2097152);
  __bf16* wt1b  = (__bf16*)take(2097152);
  __bf16* qb    = (__bf16*)take(33554432);
  __bf16* kb    = (__bf16*)take(33554432);
  __bf16* vb    = (__bf16*)take(33554432);
  float* offa   = (float*)take(8388608);
  float* psa    = (float*)take(8388608);
  float* elap   = (float*)take(65536);
  float* dl     = (float*)take(65536);
  int*   bucket = (int*)take(65536);
  float* wc_t   = (float*)take(4096);
  float* ebt    = (float*)take(36864);
  float* biasp  = (float*)take(4096);
  float* ebias  = (float*)take(12288);
  float* cw2    = (float*)take(1024);
  float* bo2    = (float*)take(1024);
  float* ebo    = (float*)take(9216);
  float* dec    = (float*)take(512);
  float* pbias  = (float*)take(512);
  if (off > ws_size) return;
  __bf16* attn_out = xb;  // alias: xb dead after G1

  F8 anc;
  {
    const double step = log2(129.0) / 7.0;
    anc.v[0] = 0.0f;
    for (int p = 1; p < 8; ++p) anc.v[p] = (float)(exp2((double)p * step) - 1.0);
  }

  k_cast2<<<17408, 256, 0, stream>>>(x, xb, Wt, wt1b);
  k_pack_all<<<dim3(256, 6), 256, 0, stream>>>(Wq, Wk, Wv, Wo, Woff, Wps, wcat, wot, w2t);
  k_prepC<<<13, 256, 0, stream>>>(bq, bk, bv, tdw, tdb, pb, ebias, dec, pbias);
  k_prepA<<<dim3(16, 10), 256, 0, stream>>>(Wc, bc, Eb, Wt, bt, wc_t, biasp, ebt);
  k_prepB<<<dim3(4, 11), 512, 0, stream>>>(wc_t, biasp, ebt, Woff, Wps, boff, bps, cw2, bo2, ebo);
  k_rowcum<<<8, 256, 0, stream>>>(td, dl, bucket, elap);

  GP gw = {};
  gw.A = w2t; gw.Bt = wt1b; gw.M = 256; gw.N = 1024; gw.K = 1024;
  gw.qb = wcat + 3145728;
  k_wcomb<<<16, 256, 0, stream>>>(gw);

  GP g1 = {};
  g1.A = xb; g1.Bt = wcat; g1.M = 16384; g1.N = 3328; g1.K = 1024;
  g1.qb = qb; g1.kb = kb; g1.vb = vb;
  g1.ebias = ebias; g1.cw2 = cw2; g1.ebo = ebo; g1.bo2 = bo2;
  g1.dl = dl; g1.bucket = bucket;
  g1.offa = offa; g1.psa = psa;
  k_g128c<0><<<128 * 26, 256, 0, stream>>>(g1);

  k_attn7<<<2048, 256, 0, stream>>>(qb, kb, vb, offa, psa, elap, dec, pbias, attn_out, anc);

  GP g3 = {};
  g3.A = attn_out; g3.Bt = wot; g3.M = 16384; g3.N = 1024; g3.K = 1024;
  g3.outp = (float*)d_out; g3.bo = bo;
  k_gemm2<2><<<64 * 4, 512, 0, stream>>>(g3);
}

// Round 14
// 407.437 us; speedup vs baseline: 1.1391x; 1.1391x over previous
//
#include <hip/hip_runtime.h>
#include <hip/hip_bf16.h>
#include <math.h>

typedef __bf16 bf16x8 __attribute__((ext_vector_type(8)));
typedef __bf16 bf16x4 __attribute__((ext_vector_type(4)));
typedef float  f32x4  __attribute__((ext_vector_type(4)));

#define S_LEN 2048
#define NB    8
#define NH    16
#define NP    8
#define DIM   1024

struct F8 { float v[8]; };

__device__ __forceinline__ void gld16(const void* g, void* l) {
  __builtin_amdgcn_global_load_lds(
      (__attribute__((address_space(1))) void*)g,
      (__attribute__((address_space(3))) void*)l, 16, 0, 0);
}

// ---------------- prep kernels ----------------

__global__ void k_cast2(const float* __restrict__ x, __bf16* __restrict__ xb,
                        const float* __restrict__ wt, __bf16* __restrict__ wt1b) {
  int i = blockIdx.x * 256 + threadIdx.x;
  const float* src; __bf16* dst;
  if (i < 4194304) { src = x; dst = xb; }
  else { i -= 4194304; if (i >= 262144) return; src = wt; dst = wt1b; }
  float4 v = reinterpret_cast<const float4*>(src)[i];
  bf16x4 o;
  o.x = (__bf16)v.x; o.y = (__bf16)v.y; o.z = (__bf16)v.z; o.w = (__bf16)v.w;
  reinterpret_cast<bf16x4*>(dst)[i] = o;
}

__global__ __launch_bounds__(256) void k_pack_all(
    const float* __restrict__ Wq, const float* __restrict__ Wk, const float* __restrict__ Wv,
    const float* __restrict__ Wo, const float* __restrict__ Woff, const float* __restrict__ Wps,
    __bf16* __restrict__ wcat, __bf16* __restrict__ wot, __bf16* __restrict__ w2t) {
  const int y = blockIdx.y;
  const float* W; __bf16* dst; int N = 1024;
  switch (y) {
    case 0: W = Wq;   dst = wcat;            break;
    case 1: W = Wk;   dst = wcat + 1048576;  break;
    case 2: W = Wv;   dst = wcat + 2097152;  break;
    case 3: W = Wo;   dst = wot;             break;
    case 4: W = Woff; dst = w2t;            N = 128; break;
    default: W = Wps; dst = w2t + 131072;   N = 128; break;
  }
  const int K = 1024;
  const int ntn = N >> 6;
  const int nblk = (K >> 6) * ntn;
  if (blockIdx.x >= nblk) return;
  __shared__ float t[64][65];
  const int bk = blockIdx.x / ntn, bn = blockIdx.x - bk * ntn;
  const int tid = threadIdx.x;
  const int c4 = tid & 15;
  const int r0 = tid >> 4;
#pragma unroll
  for (int rp = 0; rp < 4; ++rp) {
    const int row = rp * 16 + r0;
    float4 v = *(const float4*)(W + (size_t)(bk * 64 + row) * N + bn * 64 + c4 * 4);
    t[row][c4 * 4 + 0] = v.x; t[row][c4 * 4 + 1] = v.y;
    t[row][c4 * 4 + 2] = v.z; t[row][c4 * 4 + 3] = v.w;
  }
  __syncthreads();
  const int n = tid >> 2, q = tid & 3;
  bf16x8 o0, o1;
#pragma unroll
  for (int j = 0; j < 8; ++j) o0[j] = (__bf16)t[q * 16 + j][n];
#pragma unroll
  for (int j = 0; j < 8; ++j) o1[j] = (__bf16)t[q * 16 + 8 + j][n];
  __bf16* dp = dst + (size_t)(bn * 64 + n) * K + bk * 64 + q * 16;
  *(bf16x8*)dp = o0;
  *(bf16x8*)(dp + 8) = o1;
}

// parallel prep A: wc_t/biasp (y=0) and ebt rows (y=1..9); 4-way K-split, LDS reduce
__global__ __launch_bounds__(256) void k_prepA(
    const float* __restrict__ Wc, const float* __restrict__ bc,
    const float* __restrict__ Eb, const float* __restrict__ Wt,
    const float* __restrict__ bt,
    float* __restrict__ wc_t, float* __restrict__ biasp, float* __restrict__ ebt) {
  __shared__ float red[2][4][64];
  const int chunk = blockIdx.x;
  const int y = blockIdx.y;
  const int dl_ = threadIdx.x & 63, kp = threadIdx.x >> 6;
  const int d = chunk * 64 + dl_;
  float a0 = 0.f, a1 = 0.f;
  if (y == 0) {
    for (int f = kp * 64; f < kp * 64 + 64; ++f) {
      float wv = Wt[(size_t)(1024 + f) * 1024 + d];
      a0 += Wc[f] * wv;
      a1 += bc[f] * wv;
    }
  } else {
    const float* e = Eb + (y - 1) * 256;
    for (int f = kp * 64; f < kp * 64 + 64; ++f)
      a0 += e[f] * Wt[(size_t)(1280 + f) * 1024 + d];
  }
  red[0][kp][dl_] = a0;
  red[1][kp][dl_] = a1;
  __syncthreads();
  if (kp == 0) {
    float s0 = red[0][0][dl_] + red[0][1][dl_] + red[0][2][dl_] + red[0][3][dl_];
    if (y == 0) {
      float s1 = red[1][0][dl_] + red[1][1][dl_] + red[1][2][dl_] + red[1][3][dl_];
      wc_t[d] = s0;
      biasp[d] = bt[d] + s1;
    } else {
      ebt[(y - 1) * 1024 + d] = s0;
    }
  }
}

// parallel prep B: cw2 (v=0), bo2 (v=1), ebo rows (v=2..10); 8-way K-split
__global__ __launch_bounds__(512) void k_prepB(
    const float* __restrict__ wc_t, const float* __restrict__ biasp,
    const float* __restrict__ ebt,
    const float* __restrict__ Woff, const float* __restrict__ Wps,
    const float* __restrict__ boff, const float* __restrict__ bps,
    float* __restrict__ cw2, float* __restrict__ bo2, float* __restrict__ ebo) {
  __shared__ float red[8][64];
  const int chunk = blockIdx.x;
  const int v = blockIdx.y;
  const int jl = threadIdx.x & 63, kp = threadIdx.x >> 6;
  const int j = chunk * 64 + jl;
  const float* vec = (v == 0) ? wc_t : (v == 1) ? biasp : ebt + (v - 2) * 1024;
  const float* W2 = (j < 128) ? (Woff + j) : (Wps + j - 128);
  float a = 0.f;
  for (int d = kp * 128; d < kp * 128 + 128; ++d)
    a += vec[d] * W2[(size_t)d * 128];
  red[kp][jl] = a;
  __syncthreads();
  if (kp == 0) {
    float s = 0.f;
#pragma unroll
    for (int q = 0; q < 8; ++q) s += red[q][jl];
    if (v == 0)      cw2[j] = s;
    else if (v == 1) bo2[j] = s + ((j < 128) ? boff[j] : bps[j - 128]);
    else             ebo[(v - 2) * 256 + j] = s;
  }
}

// prep C: ebias concat (blocks 0-11) + dec/pbias (block 12)
__global__ void k_prepC(const float* __restrict__ bq, const float* __restrict__ bk,
                        const float* __restrict__ bv,
                        const float* __restrict__ tdw, const float* __restrict__ tdb,
                        const float* __restrict__ point_bias,
                        float* __restrict__ ebias, float* __restrict__ dec,
                        float* __restrict__ pbias) {
  const int blk = blockIdx.x, tid = threadIdx.x;
  if (blk < 12) {
    const int i = blk * 256 + tid;
    const float* src = (i < 1024) ? bq : (i < 2048) ? bk : bv;
    ebias[i] = src[i & 1023];
  } else if (tid < 128) {
    dec[tid] = log1pf(expf(tdw[tid]));
    pbias[tid] = tdb[tid] + point_bias[tid];
  }
}

__global__ void k_rowcum(const float* __restrict__ td, float* __restrict__ dl,
                         int* __restrict__ bucket, float* __restrict__ el) {
  __shared__ float part[256];
  __shared__ float pre[256];
  const int b = blockIdx.x, t = threadIdx.x;
  const float* x = td + b * S_LEN;
  float* o = el + b * S_LEN;
  const float B0[8] = {0.f, 0.5f, 1.f, 2.f, 4.f, 8.f, 12.f, 24.f};
  float loc[8];
  float run = 0.f;
#pragma unroll
  for (int j = 0; j < 8; ++j) {
    const int i = t * 8 + j;
    float dt = fmaxf(x[i], 0.f);
    dl[b * S_LEN + i] = log1pf(dt);
    int bk = 0;
#pragma unroll
    for (int q = 0; q < 8; ++q) bk += (B0[q] < dt) ? 1 : 0;
    bucket[b * S_LEN + i] = bk;
    run += dt; loc[j] = run;
  }
  part[t] = run;
  __syncthreads();
  if (t == 0) {
    float acc = 0.f;
    for (int i = 0; i < 256; ++i) { pre[i] = acc; acc += part[i]; }
  }
  __syncthreads();
  float base = pre[t];
#pragma unroll
  for (int j = 0; j < 8; ++j) o[t * 8 + j] = base + loc[j];
}

// ---------------- GEMM params ----------------

struct GP {
  const __bf16* A; const __bf16* Bt;
  int M, N, K;
  __bf16 *qb, *kb, *vb;
  const float *ebias, *cw2, *ebo, *bo2, *dl;
  const int* bucket;
  float *offa, *psa;
  float* outp; const float* bo;
};

// ---------------- G1: 128x128 tile, BK=64, 4 waves, dbuf + counted vmcnt (R12) ----------

template <int MODE>
__global__ __launch_bounds__(256) void k_g128b(GP pr) {
  __shared__ __align__(16) __bf16 As[2][128 * 64];
  __shared__ __align__(16) __bf16 Bs[2][128 * 64];
  const int tid = threadIdx.x;
  const int wave = tid >> 6, lane = tid & 63;
  const int wm = wave >> 1, wn = wave & 1;
  const int rA = lane & 15, rG = lane >> 4;

  const int nwg = gridDim.x;
  const int cpx = nwg >> 3;
  const int wg = (blockIdx.x & 7) * cpx + (blockIdx.x >> 3);

  const int nbn = pr.N >> 7;
  const int bm = wg / nbn, bn = wg - bm * nbn;
  const int m0 = bm << 7, n0 = bn << 7;
  const int K = pr.K;
  const int NT = K >> 6;

  const int srow = wave * 8 + (lane >> 3);
  const int sslot = lane & 7;

#define STGB(tt, bi) do {                                                     \
    const int k0_ = (tt) << 6;                                                \
    _Pragma("unroll")                                                         \
    for (int r = 0; r < 4; ++r) {                                             \
      const int row = r * 32 + srow;                                          \
      const int fb = r * 4096 + wave * 1024;                                  \
      const int col = k0_ + ((sslot ^ (row & 7)) << 3);                       \
      gld16(pr.A  + (size_t)(m0 + row) * K + col, (char*)As[bi] + fb);        \
      gld16(pr.Bt + (size_t)(n0 + row) * K + col, (char*)Bs[bi] + fb);        \
    }                                                                         \
  } while (0)

  f32x4 acc[4][4] = {};

  STGB(0, 0);

  int buf = 0;
  for (int t = 0; t < NT; ++t) {
    if (t + 1 < NT) {
      STGB(t + 1, buf ^ 1);
      asm volatile("s_waitcnt vmcnt(8)" ::: "memory");
    } else {
      asm volatile("s_waitcnt vmcnt(0)" ::: "memory");
    }
    __builtin_amdgcn_s_barrier();
    asm volatile("" ::: "memory");

#pragma unroll
    for (int kk = 0; kk < 2; ++kk) {
      bf16x8 af[4], bfv[4];
#pragma unroll
      for (int mt = 0; mt < 4; ++mt) {
        const int row = wm * 64 + mt * 16 + rA;
        const int slot = ((kk * 4 + rG) ^ (row & 7)) << 4;
        af[mt] = *(const bf16x8*)((const char*)As[buf] + row * 128 + slot);
      }
#pragma unroll
      for (int nt = 0; nt < 4; ++nt) {
        const int row = wn * 64 + nt * 16 + rA;
        const int slot = ((kk * 4 + rG) ^ (row & 7)) << 4;
        bfv[nt] = *(const bf16x8*)((const char*)Bs[buf] + row * 128 + slot);
      }
      __builtin_amdgcn_s_setprio(1);
#pragma unroll
      for (int mt = 0; mt < 4; ++mt)
#pragma unroll
        for (int nt = 0; nt < 4; ++nt)
          acc[mt][nt] = __builtin_amdgcn_mfma_f32_16x16x32_bf16(bfv[nt], af[mt], acc[mt][nt], 0, 0, 0);
      __builtin_amdgcn_s_setprio(0);
    }

    asm volatile("" ::: "memory");
    __builtin_amdgcn_s_barrier();
    buf ^= 1;
  }
#undef STGB

#pragma unroll
  for (int mt = 0; mt < 4; ++mt) {
    const int gr = m0 + wm * 64 + mt * 16 + rA;
    if constexpr (MODE == 0) {
      const int seg = n0 >> 10;
      if (seg < 3) {
        __bf16* dst = (seg == 0) ? pr.qb : (seg == 1) ? pr.kb : pr.vb;
        const int dbase = n0 & 1023;
        __bf16* rowp = dst + (size_t)gr * 1024;
#pragma unroll
        for (int nt = 0; nt < 4; ++nt) {
          const int d0 = dbase + wn * 64 + nt * 16 + rG * 4;
          bf16x4 o;
#pragma unroll
          for (int i = 0; i < 4; ++i)
            o[i] = (__bf16)(acc[mt][nt][i] + pr.ebias[(seg << 10) + d0 + i]);
          *(bf16x4*)(rowp + d0) = o;
        }
      } else {
        const float dlv = pr.dl[gr];
        const int bkt = pr.bucket[gr];
        const int bb = gr >> 11, ss = gr & 2047;
#pragma unroll
        for (int nt = 0; nt < 4; ++nt) {
          const int j0 = (n0 & 1023) + wn * 64 + nt * 16 + rG * 4;
#pragma unroll
          for (int i = 0; i < 4; ++i) {
            const int j = j0 + i;
            float v = acc[mt][nt][i] + dlv * pr.cw2[j] + pr.ebo[bkt * 256 + j] + pr.bo2[j];
            if (j < 128) {
              const int hh = j >> 3, pp = j & 7;
              pr.offa[(((size_t)bb * NH + hh) * S_LEN + ss) * NP + pp] = tanhf(v);
            } else {
              const int jj = j - 128, hh = jj >> 3, pp = jj & 7;
              pr.psa[(((size_t)bb * NH + hh) * S_LEN + ss) * NP + pp] = v;
            }
          }
        }
      }
    } else {
      float* rowp = pr.outp + (size_t)gr * 1024;
#pragma unroll
      for (int nt = 0; nt < 4; ++nt) {
        const int d0 = n0 + wn * 64 + nt * 16 + rG * 4;
        f32x4 o;
#pragma unroll
        for (int i = 0; i < 4; ++i) o[i] = acc[mt][nt][i] + pr.bo[d0 + i];
        *(f32x4*)(rowp + d0) = o;
      }
    }
  }
}

// ---------------- G3: 256x256, BK=64, 8 waves, counted vmcnt (R8-proven) ---------------

template <int MODE>
__global__ __launch_bounds__(512, 2) void k_gemm2(GP pr) {
  __shared__ __align__(16) __bf16 As[2][256 * 64];
  __shared__ __align__(16) __bf16 Bs[2][256 * 64];
  const int tid = threadIdx.x;
  const int wave = tid >> 6, lane = tid & 63;
  const int wm = wave >> 2, wn = wave & 3;
  const int rA = lane & 15, rG = lane >> 4;

  const int nwg = gridDim.x;
  const int cpx = nwg >> 3;
  const int wg = (blockIdx.x & 7) * cpx + (blockIdx.x >> 3);

  const int nbn = pr.N >> 8;
  const int bm = wg / nbn, bn = wg - bm * nbn;
  const int m0 = bm << 8, n0 = bn << 8;
  const int K = pr.K;
  const int NT = K >> 6;

  const int srow = wave * 8 + (lane >> 3);
  const int sslot = lane & 7;

  f32x4 acc[8][4] = {};

#pragma unroll
  for (int r = 0; r < 4; ++r) {
    const int row = r * 64 + srow;
    const int fb = r * 8192 + wave * 1024;
    const int col = (sslot ^ (row & 7)) << 3;
    gld16(pr.A  + (size_t)(m0 + row) * K + col, (char*)As[0] + fb);
    gld16(pr.Bt + (size_t)(n0 + row) * K + col, (char*)Bs[0] + fb);
  }

  int buf = 0;
  for (int t = 0; t < NT; ++t) {
    if (t + 1 < NT) {
      const int k0 = (t + 1) << 6;
#pragma unroll
      for (int r = 0; r < 4; ++r) {
        const int row = r * 64 + srow;
        const int fb = r * 8192 + wave * 1024;
        const int col = k0 + ((sslot ^ (row & 7)) << 3);
        gld16(pr.A  + (size_t)(m0 + row) * K + col, (char*)As[buf ^ 1] + fb);
        gld16(pr.Bt + (size_t)(n0 + row) * K + col, (char*)Bs[buf ^ 1] + fb);
      }
      asm volatile("s_waitcnt vmcnt(8)" ::: "memory");
    } else {
      asm volatile("s_waitcnt vmcnt(0)" ::: "memory");
    }
    __builtin_amdgcn_s_barrier();
    asm volatile("" ::: "memory");

#pragma unroll
    for (int kk = 0; kk < 2; ++kk) {
      bf16x8 af[8], bfv[4];
#pragma unroll
      for (int mt = 0; mt < 8; ++mt) {
        const int row = wm * 128 + mt * 16 + rA;
        const int slot = ((kk * 4 + rG) ^ (row & 7)) << 4;
        af[mt] = *(const bf16x8*)((const char*)As[buf] + row * 128 + slot);
      }
#pragma unroll
      for (int nt = 0; nt < 4; ++nt) {
        const int row = wn * 64 + nt * 16 + rA;
        const int slot = ((kk * 4 + rG) ^ (row & 7)) << 4;
        bfv[nt] = *(const bf16x8*)((const char*)Bs[buf] + row * 128 + slot);
      }
      __builtin_amdgcn_s_setprio(1);
#pragma unroll
      for (int mt = 0; mt < 8; ++mt)
#pragma unroll
        for (int nt = 0; nt < 4; ++nt)
          acc[mt][nt] = __builtin_amdgcn_mfma_f32_16x16x32_bf16(bfv[nt], af[mt], acc[mt][nt], 0, 0, 0);
      __builtin_amdgcn_s_setprio(0);
    }
    asm volatile("" ::: "memory");
    __builtin_amdgcn_s_barrier();
    buf ^= 1;
  }

#pragma unroll
  for (int mt = 0; mt < 8; ++mt) {
    const int gr = m0 + wm * 128 + mt * 16 + rA;
    float* rowp = pr.outp + (size_t)gr * 1024;
#pragma unroll
    for (int nt = 0; nt < 4; ++nt) {
      const int d0 = n0 + wn * 64 + nt * 16 + rG * 4;
      f32x4 o;
#pragma unroll
      for (int i = 0; i < 4; ++i) o[i] = acc[mt][nt][i] + pr.bo[d0 + i];
      *(f32x4*)(rowp + d0) = o;
    }
  }
}

// ---------------- 128x128 m97-style GEMM: combined-weight prep ----------------

__global__ __launch_bounds__(256) void k_wcomb(GP pr) {
  __shared__ __bf16 As[128 * 32];
  __shared__ __bf16 Bs[128 * 32];
  const int tid = threadIdx.x;
  const int wave = tid >> 6, lane = tid & 63;
  const int wm = wave >> 1, wn = wave & 1;
  const int nbn = pr.N >> 7;
  const int bm = blockIdx.x / nbn, bn = blockIdx.x - bm * nbn;
  const int m0 = bm << 7, n0 = bn << 7;
  const int K = pr.K;
  const int rA = lane & 15, rG = lane >> 4;

  f32x4 acc[4][4] = {};

  for (int k0 = 0; k0 < K; k0 += 32) {
#pragma unroll
    for (int ch = 0; ch < 2; ++ch) {
      const int fb = ch * 4096 + wave * 1024;
      const int e = (fb >> 1) + lane * 8;
      const int row = e >> 5, col = e & 31;
      gld16(pr.A  + (size_t)(m0 + row) * K + (k0 + col), (char*)As + fb);
      gld16(pr.Bt + (size_t)(n0 + row) * K + (k0 + col), (char*)Bs + fb);
    }
    __syncthreads();

    bf16x8 af[4], bfv[4];
#pragma unroll
    for (int mt = 0; mt < 4; ++mt)
      af[mt] = *(const bf16x8*)&As[(wm * 64 + mt * 16 + rA) * 32 + rG * 8];
#pragma unroll
    for (int nt = 0; nt < 4; ++nt)
      bfv[nt] = *(const bf16x8*)&Bs[(wn * 64 + nt * 16 + rA) * 32 + rG * 8];
#pragma unroll
    for (int mt = 0; mt < 4; ++mt)
#pragma unroll
      for (int nt = 0; nt < 4; ++nt)
        acc[mt][nt] = __builtin_amdgcn_mfma_f32_16x16x32_bf16(af[mt], bfv[nt], acc[mt][nt], 0, 0, 0);
    __syncthreads();
  }

#pragma unroll
  for (int mt = 0; mt < 4; ++mt) {
#pragma unroll
    for (int nt = 0; nt < 4; ++nt) {
      const int gc = n0 + wn * 64 + nt * 16 + rA;
      const int grb = m0 + wm * 64 + mt * 16 + rG * 4;
#pragma unroll
      for (int i = 0; i < 4; ++i)
        pr.qb[(size_t)(grb + i) * 1024 + gc] = (__bf16)acc[mt][nt][i];
    }
  }
}

// ---------------- deformable attention v6b: LDS K + flipped lanes + fast math ----------

#define ATILE 128
#define AROWS 266
#define ARST  72

__global__ __launch_bounds__(256) void k_attn6(
    const __bf16* __restrict__ qb, const __bf16* __restrict__ kb, const __bf16* __restrict__ vb,
    const float* __restrict__ offa, const float* __restrict__ psa,
    const float* __restrict__ elapsed,
    const float* __restrict__ dec, const float* __restrict__ pbias,
    __bf16* __restrict__ attn_out, F8 anchors) {
  __shared__ __align__(16) __bf16 lk[AROWS * ARST];
  __shared__ float lel[AROWS];

  const int bid = blockIdx.x;
  const int t0 = bid & 15, h = (bid >> 4) & 15, b = bid >> 8;
  const int s0 = t0 * ATILE;
  const int lo = (s0 > 136) ? (s0 - 136) : 0;
  const int tid = threadIdx.x;
  const size_t bBase = (size_t)b * S_LEN;
  const int hd0 = h * 64;

  for (int idx = tid; idx < AROWS * 8; idx += 256) {
    const int row = idx >> 3, c8 = idx & 7;
    int gr = lo + row; if (gr > S_LEN - 1) gr = S_LEN - 1;
    *(bf16x8*)(lk + row * ARST + c8 * 8) =
        *(const bf16x8*)(kb + (bBase + gr) * DIM + hd0 + c8 * 8);
  }
  for (int idx = tid; idx < AROWS; idx += 256) {
    int gr = lo + idx; if (gr > S_LEN - 1) gr = S_LEN - 1;
    lel[idx] = elapsed[b * S_LEN + gr];
  }
  __syncthreads();

  const int wv = tid >> 6, lane = tid & 63;
  const int p = lane & 7, c = lane >> 3;        // p in low bits
  const int pb0 = p & 1, pb1 = (p >> 1) & 1, pb2 = p >> 2;
  const float anchor = anchors.v[p];
  const int hp = h * NP + p;
  const float decv = dec[hp], pbv = pbias[hp];

  const int sw0 = s0 + wv * 32;
  const __bf16* vbase = vb + bBase * DIM + hd0 + c * 8;
  const __bf16* qbase = qb + bBase * DIM + hd0 + c * 8;
  size_t ppos0 = (((size_t)b * NH + h) * S_LEN + sw0) * NP + p;

#pragma unroll 2
  for (int i = 0; i < 32; ++i) {
    const int s = sw0 + i;
    const float off = offa[ppos0 + (size_t)i * NP];
    const float psv = psa[ppos0 + (size_t)i * NP];
    const bf16x8 qv = *(const bf16x8*)(qbase + (size_t)s * DIM);

    float pos = (float)s - anchor + off * 8.0f;
    pos = fminf(fmaxf(pos, 0.0f), (float)s);
    int li = (int)pos;
    const float alpha = pos - (float)li;
    int ri = li + 1; if (ri > S_LEN - 1) ri = S_LEN - 1;
    const int lr = li - lo, rr = ri - lo;

    const bf16x8 vl = *(const bf16x8*)(vbase + (size_t)li * DIM);
    const bf16x8 vr = *(const bf16x8*)(vbase + (size_t)ri * DIM);

    const bf16x8 kl = *(const bf16x8*)(lk + lr * ARST + c * 8);
    const bf16x8 kr = *(const bf16x8*)(lk + rr * ARST + c * 8);
    float dpl = 0.f, dpr = 0.f;
#pragma unroll
    for (int j = 0; j < 8; ++j) {
      dpl += (float)qv[j] * (float)kl[j];
      dpr += (float)qv[j] * (float)kr[j];
    }
    float dot = dpl + alpha * (dpr - dpl);
    dot += __shfl_xor(dot, 8);    // reduce over c (wide masks)
    dot += __shfl_xor(dot, 16);
    dot += __shfl_xor(dot, 32);

    const float el_s = lel[s - lo];
    const float ell = lel[lr];
    const float elr2 = lel[rr];
    const float elsamp = ell + alpha * (elr2 - ell);
    const float relarg = fmaxf(el_s - elsamp, 0.f);
    const float rel = __logf(1.0f + relarg);
    const float score = dot * 0.125f + psv + pbv - decv * rel;

    const float e = __expf(score);
    float dsum = e;                // reduce over p (narrow masks)
    dsum += __shfl_xor(dsum, 1);
    dsum += __shfl_xor(dsum, 2);
    dsum += __shfl_xor(dsum, 4);
    const float wgt = e * __builtin_amdgcn_rcpf(dsum);
    const float wl = wgt * (1.0f - alpha), wr = wgt * alpha;

    float o[8];
#pragma unroll
    for (int j = 0; j < 8; ++j)
      o[j] = wl * (float)vl[j] + wr * (float)vr[j];

    // butterfly over p (masks 1/2/4): lane (c,p) ends with channel c*8+p
    float r00 = (pb0 ? o[1] : o[0]) + __shfl_xor(pb0 ? o[0] : o[1], 1);
    float r01 = (pb0 ? o[3] : o[2]) + __shfl_xor(pb0 ? o[2] : o[3], 1);
    float r02 = (pb0 ? o[5] : o[4]) + __shfl_xor(pb0 ? o[4] : o[5], 1);
    float r03 = (pb0 ? o[7] : o[6]) + __shfl_xor(pb0 ? o[6] : o[7], 1);
    float r10 = (pb1 ? r01 : r00) + __shfl_xor(pb1 ? r00 : r01, 2);
    float r11 = (pb1 ? r03 : r02) + __shfl_xor(pb1 ? r02 : r03, 2);
    float rf = (pb2 ? r11 : r10) + __shfl_xor(pb2 ? r10 : r11, 4);

    attn_out[(bBase + s) * DIM + hd0 + c * 8 + p] = (__bf16)rf;
  }
}

// ---------------- host ----------------

extern "C" void kernel_launch(void* const* d_in, const int* in_sizes, int n_in,
                              void* d_out, int out_size, void* d_ws, size_t ws_size,
                              hipStream_t stream) {
  const float* x    = (const float*)d_in[0];
  const float* td   = (const float*)d_in[1];
  const float* Wq   = (const float*)d_in[2];
  const float* bq   = (const float*)d_in[3];
  const float* Wk   = (const float*)d_in[4];
  const float* bk   = (const float*)d_in[5];
  const float* Wv   = (const float*)d_in[6];
  const float* bv   = (const float*)d_in[7];
  const float* Wc   = (const float*)d_in[8];
  const float* bc   = (const float*)d_in[9];
  const float* Eb   = (const float*)d_in[10];
  const float* Wt   = (const float*)d_in[11];
  const float* bt   = (const float*)d_in[12];
  const float* Woff = (const float*)d_in[13];
  const float* boff = (const float*)d_in[14];
  const float* Wps  = (const float*)d_in[15];
  const float* bps  = (const float*)d_in[16];
  const float* Wo   = (const float*)d_in[17];
  const float* bo   = (const float*)d_in[18];
  const float* pb   = (const float*)d_in[19];
  const float* tdw  = (const float*)d_in[20];
  const float* tdb  = (const float*)d_in[21];

  char* w = (char*)d_ws;
  size_t off = 0;
  auto take = [&](size_t n) {
    char* pp = w + off;
    off += (n + 255) & ~(size_t)255;
    return pp;
  };
  __bf16* xb    = (__bf16*)take(33554432);
  __bf16* wcat  = (__bf16*)take(8388608);
  __bf16* w2t   = (__bf16*)take(524288);
  __bf16* wot   = (__bf16*)take(2097152);
  __bf16* wt1b  = (__bf16*)take(2097152);
  __bf16* qb    = (__bf16*)take(33554432);
  __bf16* kb    = (__bf16*)take(33554432);
  __bf16* vb    = (__bf16*)take(33554432);
  float* offa   = (float*)take(8388608);
  float* psa    = (float*)take(8388608);
  float* elap   = (float*)take(65536);
  float* dl     = (float*)take(65536);
  int*   bucket = (int*)take(65536);
  float* wc_t   = (float*)take(4096);
  float* ebt    = (float*)take(36864);
  float* biasp  = (float*)take(4096);
  float* ebias  = (float*)take(12288);
  float* cw2    = (float*)take(1024);
  float* bo2    = (float*)take(1024);
  float* ebo    = (float*)take(9216);
  float* dec    = (float*)take(512);
  float* pbias  = (float*)take(512);
  if (off > ws_size) return;
  __bf16* attn_out = xb;  // alias: xb dead after G1

  F8 anc;
  {
    const double step = log2(129.0) / 7.0;
    anc.v[0] = 0.0f;
    for (int p = 1; p < 8; ++p) anc.v[p] = (float)(exp2((double)p * step) - 1.0);
  }

  k_cast2<<<17408, 256, 0, stream>>>(x, xb, Wt, wt1b);
  k_pack_all<<<dim3(256, 6), 256, 0, stream>>>(Wq, Wk, Wv, Wo, Woff, Wps, wcat, wot, w2t);
  k_prepC<<<13, 256, 0, stream>>>(bq, bk, bv, tdw, tdb, pb, ebias, dec, pbias);
  k_prepA<<<dim3(16, 10), 256, 0, stream>>>(Wc, bc, Eb, Wt, bt, wc_t, biasp, ebt);
  k_prepB<<<dim3(4, 11), 512, 0, stream>>>(wc_t, biasp, ebt, Woff, Wps, boff, bps, cw2, bo2, ebo);
  k_rowcum<<<8, 256, 0, stream>>>(td, dl, bucket, elap);

  GP gw = {};
  gw.A = w2t; gw.Bt = wt1b; gw.M = 256; gw.N = 1024; gw.K = 1024;
  gw.qb = wcat + 3145728;
  k_wcomb<<<16, 256, 0, stream>>>(gw);

  GP g1 = {};
  g1.A = xb; g1.Bt = wcat; g1.M = 16384; g1.N = 3328; g1.K = 1024;
  g1.qb = qb; g1.kb = kb; g1.vb = vb;
  g1.ebias = ebias; g1.cw2 = cw2; g1.ebo = ebo; g1.bo2 = bo2;
  g1.dl = dl; g1.bucket = bucket;
  g1.offa = offa; g1.psa = psa;
  k_g128b<0><<<128 * 26, 256, 0, stream>>>(g1);

  k_attn6<<<2048, 256, 0, stream>>>(qb, kb, vb, offa, psa, elap, dec, pbias, attn_out, anc);

  GP g3 = {};
  g3.A = attn_out; g3.Bt = wot; g3.M = 16384; g3.N = 1024; g3.K = 1024;
  g3.outp = (float*)d_out; g3.bo = bo;
  k_gemm2<2><<<64 * 4, 512, 0, stream>>>(g3);
}

// Round 15
// 404.670 us; speedup vs baseline: 1.1469x; 1.0068x over previous
//
#include <hip/hip_runtime.h>
#include <hip/hip_bf16.h>
#include <math.h>

typedef __bf16 bf16x8 __attribute__((ext_vector_type(8)));
typedef __bf16 bf16x4 __attribute__((ext_vector_type(4)));
typedef float  f32x4  __attribute__((ext_vector_type(4)));

#define S_LEN 2048
#define NB    8
#define NH    16
#define NP    8
#define DIM   1024

struct F8 { float v[8]; };

__device__ __forceinline__ void gld16(const void* g, void* l) {
  __builtin_amdgcn_global_load_lds(
      (__attribute__((address_space(1))) void*)g,
      (__attribute__((address_space(3))) void*)l, 16, 0, 0);
}

// ---------------- prep kernels ----------------

__global__ void k_cast2(const float* __restrict__ x, __bf16* __restrict__ xb,
                        const float* __restrict__ wt, __bf16* __restrict__ wt1b) {
  int i = blockIdx.x * 256 + threadIdx.x;
  const float* src; __bf16* dst;
  if (i < 4194304) { src = x; dst = xb; }
  else { i -= 4194304; if (i >= 262144) return; src = wt; dst = wt1b; }
  float4 v = reinterpret_cast<const float4*>(src)[i];
  bf16x4 o;
  o.x = (__bf16)v.x; o.y = (__bf16)v.y; o.z = (__bf16)v.z; o.w = (__bf16)v.w;
  reinterpret_cast<bf16x4*>(dst)[i] = o;
}

__global__ __launch_bounds__(256) void k_pack_all(
    const float* __restrict__ Wq, const float* __restrict__ Wk, const float* __restrict__ Wv,
    const float* __restrict__ Wo, const float* __restrict__ Woff, const float* __restrict__ Wps,
    __bf16* __restrict__ wcat, __bf16* __restrict__ wot, __bf16* __restrict__ w2t) {
  const int y = blockIdx.y;
  const float* W; __bf16* dst; int N = 1024;
  switch (y) {
    case 0: W = Wq;   dst = wcat;            break;
    case 1: W = Wk;   dst = wcat + 1048576;  break;
    case 2: W = Wv;   dst = wcat + 2097152;  break;
    case 3: W = Wo;   dst = wot;             break;
    case 4: W = Woff; dst = w2t;            N = 128; break;
    default: W = Wps; dst = w2t + 131072;   N = 128; break;
  }
  const int K = 1024;
  const int ntn = N >> 6;
  const int nblk = (K >> 6) * ntn;
  if (blockIdx.x >= nblk) return;
  __shared__ float t[64][65];
  const int bk = blockIdx.x / ntn, bn = blockIdx.x - bk * ntn;
  const int tid = threadIdx.x;
  const int c4 = tid & 15;
  const int r0 = tid >> 4;
#pragma unroll
  for (int rp = 0; rp < 4; ++rp) {
    const int row = rp * 16 + r0;
    float4 v = *(const float4*)(W + (size_t)(bk * 64 + row) * N + bn * 64 + c4 * 4);
    t[row][c4 * 4 + 0] = v.x; t[row][c4 * 4 + 1] = v.y;
    t[row][c4 * 4 + 2] = v.z; t[row][c4 * 4 + 3] = v.w;
  }
  __syncthreads();
  const int n = tid >> 2, q = tid & 3;
  bf16x8 o0, o1;
#pragma unroll
  for (int j = 0; j < 8; ++j) o0[j] = (__bf16)t[q * 16 + j][n];
#pragma unroll
  for (int j = 0; j < 8; ++j) o1[j] = (__bf16)t[q * 16 + 8 + j][n];
  __bf16* dp = dst + (size_t)(bn * 64 + n) * K + bk * 64 + q * 16;
  *(bf16x8*)dp = o0;
  *(bf16x8*)(dp + 8) = o1;
}

// parallel prep A: wc_t/biasp (y=0) and ebt rows (y=1..9); 4-way K-split, LDS reduce
__global__ __launch_bounds__(256) void k_prepA(
    const float* __restrict__ Wc, const float* __restrict__ bc,
    const float* __restrict__ Eb, const float* __restrict__ Wt,
    const float* __restrict__ bt,
    float* __restrict__ wc_t, float* __restrict__ biasp, float* __restrict__ ebt) {
  __shared__ float red[2][4][64];
  const int chunk = blockIdx.x;
  const int y = blockIdx.y;
  const int dl_ = threadIdx.x & 63, kp = threadIdx.x >> 6;
  const int d = chunk * 64 + dl_;
  float a0 = 0.f, a1 = 0.f;
  if (y == 0) {
    for (int f = kp * 64; f < kp * 64 + 64; ++f) {
      float wv = Wt[(size_t)(1024 + f) * 1024 + d];
      a0 += Wc[f] * wv;
      a1 += bc[f] * wv;
    }
  } else {
    const float* e = Eb + (y - 1) * 256;
    for (int f = kp * 64; f < kp * 64 + 64; ++f)
      a0 += e[f] * Wt[(size_t)(1280 + f) * 1024 + d];
  }
  red[0][kp][dl_] = a0;
  red[1][kp][dl_] = a1;
  __syncthreads();
  if (kp == 0) {
    float s0 = red[0][0][dl_] + red[0][1][dl_] + red[0][2][dl_] + red[0][3][dl_];
    if (y == 0) {
      float s1 = red[1][0][dl_] + red[1][1][dl_] + red[1][2][dl_] + red[1][3][dl_];
      wc_t[d] = s0;
      biasp[d] = bt[d] + s1;
    } else {
      ebt[(y - 1) * 1024 + d] = s0;
    }
  }
}

// parallel prep B: cw2 (v=0), bo2 (v=1), ebo rows (v=2..10); 8-way K-split
__global__ __launch_bounds__(512) void k_prepB(
    const float* __restrict__ wc_t, const float* __restrict__ biasp,
    const float* __restrict__ ebt,
    const float* __restrict__ Woff, const float* __restrict__ Wps,
    const float* __restrict__ boff, const float* __restrict__ bps,
    float* __restrict__ cw2, float* __restrict__ bo2, float* __restrict__ ebo) {
  __shared__ float red[8][64];
  const int chunk = blockIdx.x;
  const int v = blockIdx.y;
  const int jl = threadIdx.x & 63, kp = threadIdx.x >> 6;
  const int j = chunk * 64 + jl;
  const float* vec = (v == 0) ? wc_t : (v == 1) ? biasp : ebt + (v - 2) * 1024;
  const float* W2 = (j < 128) ? (Woff + j) : (Wps + j - 128);
  float a = 0.f;
  for (int d = kp * 128; d < kp * 128 + 128; ++d)
    a += vec[d] * W2[(size_t)d * 128];
  red[kp][jl] = a;
  __syncthreads();
  if (kp == 0) {
    float s = 0.f;
#pragma unroll
    for (int q = 0; q < 8; ++q) s += red[q][jl];
    if (v == 0)      cw2[j] = s;
    else if (v == 1) bo2[j] = s + ((j < 128) ? boff[j] : bps[j - 128]);
    else             ebo[(v - 2) * 256 + j] = s;
  }
}

// prep C: ebias concat (blocks 0-11) + dec/pbias (block 12)
__global__ void k_prepC(const float* __restrict__ bq, const float* __restrict__ bk,
                        const float* __restrict__ bv,
                        const float* __restrict__ tdw, const float* __restrict__ tdb,
                        const float* __restrict__ point_bias,
                        float* __restrict__ ebias, float* __restrict__ dec,
                        float* __restrict__ pbias) {
  const int blk = blockIdx.x, tid = threadIdx.x;
  if (blk < 12) {
    const int i = blk * 256 + tid;
    const float* src = (i < 1024) ? bq : (i < 2048) ? bk : bv;
    ebias[i] = src[i & 1023];
  } else if (tid < 128) {
    dec[tid] = log1pf(expf(tdw[tid]));
    pbias[tid] = tdb[tid] + point_bias[tid];
  }
}

__global__ void k_rowcum(const float* __restrict__ td, float* __restrict__ dl,
                         int* __restrict__ bucket, float* __restrict__ el) {
  __shared__ float part[256];
  __shared__ float pre[256];
  const int b = blockIdx.x, t = threadIdx.x;
  const float* x = td + b * S_LEN;
  float* o = el + b * S_LEN;
  const float B0[8] = {0.f, 0.5f, 1.f, 2.f, 4.f, 8.f, 12.f, 24.f};
  float loc[8];
  float run = 0.f;
#pragma unroll
  for (int j = 0; j < 8; ++j) {
    const int i = t * 8 + j;
    float dt = fmaxf(x[i], 0.f);
    dl[b * S_LEN + i] = log1pf(dt);
    int bk = 0;
#pragma unroll
    for (int q = 0; q < 8; ++q) bk += (B0[q] < dt) ? 1 : 0;
    bucket[b * S_LEN + i] = bk;
    run += dt; loc[j] = run;
  }
  part[t] = run;
  __syncthreads();
  if (t == 0) {
    float acc = 0.f;
    for (int i = 0; i < 256; ++i) { pre[i] = acc; acc += part[i]; }
  }
  __syncthreads();
  float base = pre[t];
#pragma unroll
  for (int j = 0; j < 8; ++j) o[t * 8 + j] = base + loc[j];
}

// ---------------- GEMM params ----------------

struct GP {
  const __bf16* A; const __bf16* Bt;
  int M, N, K;
  __bf16 *qb, *kb, *vb;
  const float *ebias, *cw2, *ebo, *bo2, *dl;
  const int* bucket;
  float *offa, *psa;
  float* outp; const float* bo;
};

// ---------------- G1: 128x128 tile, BK=64, 4 waves, dbuf + counted vmcnt (R12) ----------
// MODE 0: L2-partitioned block map (N=3328, 26 bn): XCDs 0-3 own bn 0-12, XCDs 4-7 own
// bn 13-25; each XCD owns a 32-row bm quarter, bn innermost. Per-XCD B set = 3.3MB ->
// L2-resident; A-tile reused 13x while hot. Bijective (xcd,idx) <-> (bm,bn).

template <int MODE>
__global__ __launch_bounds__(256) void k_g128b(GP pr) {
  __shared__ __align__(16) __bf16 As[2][128 * 64];
  __shared__ __align__(16) __bf16 Bs[2][128 * 64];
  const int tid = threadIdx.x;
  const int wave = tid >> 6, lane = tid & 63;
  const int wm = wave >> 1, wn = wave & 1;
  const int rA = lane & 15, rG = lane >> 4;

  int bm, bn;
  if constexpr (MODE == 0) {
    const int xcd = blockIdx.x & 7;
    const int idx = blockIdx.x >> 3;        // 0..415 = 32 bm x 13 bn
    const int bmi = idx / 13, bni = idx - bmi * 13;
    bm = (xcd & 3) * 32 + bmi;
    bn = (xcd >> 2) * 13 + bni;
  } else {
    const int nwg = gridDim.x;
    const int cpx = nwg >> 3;
    const int wg = (blockIdx.x & 7) * cpx + (blockIdx.x >> 3);
    const int nbn = pr.N >> 7;
    bm = wg / nbn; bn = wg - bm * nbn;
  }
  const int m0 = bm << 7, n0 = bn << 7;
  const int K = pr.K;
  const int NT = K >> 6;

  const int srow = wave * 8 + (lane >> 3);
  const int sslot = lane & 7;

#define STGB(tt, bi) do {                                                     \
    const int k0_ = (tt) << 6;                                                \
    _Pragma("unroll")                                                         \
    for (int r = 0; r < 4; ++r) {                                             \
      const int row = r * 32 + srow;                                          \
      const int fb = r * 4096 + wave * 1024;                                  \
      const int col = k0_ + ((sslot ^ (row & 7)) << 3);                       \
      gld16(pr.A  + (size_t)(m0 + row) * K + col, (char*)As[bi] + fb);        \
      gld16(pr.Bt + (size_t)(n0 + row) * K + col, (char*)Bs[bi] + fb);        \
    }                                                                         \
  } while (0)

  f32x4 acc[4][4] = {};

  STGB(0, 0);

  int buf = 0;
  for (int t = 0; t < NT; ++t) {
    if (t + 1 < NT) {
      STGB(t + 1, buf ^ 1);
      asm volatile("s_waitcnt vmcnt(8)" ::: "memory");
    } else {
      asm volatile("s_waitcnt vmcnt(0)" ::: "memory");
    }
    __builtin_amdgcn_s_barrier();
    asm volatile("" ::: "memory");

#pragma unroll
    for (int kk = 0; kk < 2; ++kk) {
      bf16x8 af[4], bfv[4];
#pragma unroll
      for (int mt = 0; mt < 4; ++mt) {
        const int row = wm * 64 + mt * 16 + rA;
        const int slot = ((kk * 4 + rG) ^ (row & 7)) << 4;
        af[mt] = *(const bf16x8*)((const char*)As[buf] + row * 128 + slot);
      }
#pragma unroll
      for (int nt = 0; nt < 4; ++nt) {
        const int row = wn * 64 + nt * 16 + rA;
        const int slot = ((kk * 4 + rG) ^ (row & 7)) << 4;
        bfv[nt] = *(const bf16x8*)((const char*)Bs[buf] + row * 128 + slot);
      }
      __builtin_amdgcn_s_setprio(1);
#pragma unroll
      for (int mt = 0; mt < 4; ++mt)
#pragma unroll
        for (int nt = 0; nt < 4; ++nt)
          acc[mt][nt] = __builtin_amdgcn_mfma_f32_16x16x32_bf16(bfv[nt], af[mt], acc[mt][nt], 0, 0, 0);
      __builtin_amdgcn_s_setprio(0);
    }

    asm volatile("" ::: "memory");
    __builtin_amdgcn_s_barrier();
    buf ^= 1;
  }
#undef STGB

#pragma unroll
  for (int mt = 0; mt < 4; ++mt) {
    const int gr = m0 + wm * 64 + mt * 16 + rA;
    if constexpr (MODE == 0) {
      const int seg = n0 >> 10;
      if (seg < 3) {
        __bf16* dst = (seg == 0) ? pr.qb : (seg == 1) ? pr.kb : pr.vb;
        const int dbase = n0 & 1023;
        __bf16* rowp = dst + (size_t)gr * 1024;
#pragma unroll
        for (int nt = 0; nt < 4; ++nt) {
          const int d0 = dbase + wn * 64 + nt * 16 + rG * 4;
          bf16x4 o;
#pragma unroll
          for (int i = 0; i < 4; ++i)
            o[i] = (__bf16)(acc[mt][nt][i] + pr.ebias[(seg << 10) + d0 + i]);
          *(bf16x4*)(rowp + d0) = o;
        }
      } else {
        const float dlv = pr.dl[gr];
        const int bkt = pr.bucket[gr];
        const int bb = gr >> 11, ss = gr & 2047;
#pragma unroll
        for (int nt = 0; nt < 4; ++nt) {
          const int j0 = (n0 & 1023) + wn * 64 + nt * 16 + rG * 4;
#pragma unroll
          for (int i = 0; i < 4; ++i) {
            const int j = j0 + i;
            float v = acc[mt][nt][i] + dlv * pr.cw2[j] + pr.ebo[bkt * 256 + j] + pr.bo2[j];
            if (j < 128) {
              const int hh = j >> 3, pp = j & 7;
              pr.offa[(((size_t)bb * NH + hh) * S_LEN + ss) * NP + pp] = tanhf(v);
            } else {
              const int jj = j - 128, hh = jj >> 3, pp = jj & 7;
              pr.psa[(((size_t)bb * NH + hh) * S_LEN + ss) * NP + pp] = v;
            }
          }
        }
      }
    } else {
      float* rowp = pr.outp + (size_t)gr * 1024;
#pragma unroll
      for (int nt = 0; nt < 4; ++nt) {
        const int d0 = n0 + wn * 64 + nt * 16 + rG * 4;
        f32x4 o;
#pragma unroll
        for (int i = 0; i < 4; ++i) o[i] = acc[mt][nt][i] + pr.bo[d0 + i];
        *(f32x4*)(rowp + d0) = o;
      }
    }
  }
}

// ---------------- G3: 256x256, BK=64, 8 waves, counted vmcnt (R8-proven) ---------------

template <int MODE>
__global__ __launch_bounds__(512, 2) void k_gemm2(GP pr) {
  __shared__ __align__(16) __bf16 As[2][256 * 64];
  __shared__ __align__(16) __bf16 Bs[2][256 * 64];
  const int tid = threadIdx.x;
  const int wave = tid >> 6, lane = tid & 63;
  const int wm = wave >> 2, wn = wave & 3;
  const int rA = lane & 15, rG = lane >> 4;

  const int nwg = gridDim.x;
  const int cpx = nwg >> 3;
  const int wg = (blockIdx.x & 7) * cpx + (blockIdx.x >> 3);

  const int nbn = pr.N >> 8;
  const int bm = wg / nbn, bn = wg - bm * nbn;
  const int m0 = bm << 8, n0 = bn << 8;
  const int K = pr.K;
  const int NT = K >> 6;

  const int srow = wave * 8 + (lane >> 3);
  const int sslot = lane & 7;

  f32x4 acc[8][4] = {};

#pragma unroll
  for (int r = 0; r < 4; ++r) {
    const int row = r * 64 + srow;
    const int fb = r * 8192 + wave * 1024;
    const int col = (sslot ^ (row & 7)) << 3;
    gld16(pr.A  + (size_t)(m0 + row) * K + col, (char*)As[0] + fb);
    gld16(pr.Bt + (size_t)(n0 + row) * K + col, (char*)Bs[0] + fb);
  }

  int buf = 0;
  for (int t = 0; t < NT; ++t) {
    if (t + 1 < NT) {
      const int k0 = (t + 1) << 6;
#pragma unroll
      for (int r = 0; r < 4; ++r) {
        const int row = r * 64 + srow;
        const int fb = r * 8192 + wave * 1024;
        const int col = k0 + ((sslot ^ (row & 7)) << 3);
        gld16(pr.A  + (size_t)(m0 + row) * K + col, (char*)As[buf ^ 1] + fb);
        gld16(pr.Bt + (size_t)(n0 + row) * K + col, (char*)Bs[buf ^ 1] + fb);
      }
      asm volatile("s_waitcnt vmcnt(8)" ::: "memory");
    } else {
      asm volatile("s_waitcnt vmcnt(0)" ::: "memory");
    }
    __builtin_amdgcn_s_barrier();
    asm volatile("" ::: "memory");

#pragma unroll
    for (int kk = 0; kk < 2; ++kk) {
      bf16x8 af[8], bfv[4];
#pragma unroll
      for (int mt = 0; mt < 8; ++mt) {
        const int row = wm * 128 + mt * 16 + rA;
        const int slot = ((kk * 4 + rG) ^ (row & 7)) << 4;
        af[mt] = *(const bf16x8*)((const char*)As[buf] + row * 128 + slot);
      }
#pragma unroll
      for (int nt = 0; nt < 4; ++nt) {
        const int row = wn * 64 + nt * 16 + rA;
        const int slot = ((kk * 4 + rG) ^ (row & 7)) << 4;
        bfv[nt] = *(const bf16x8*)((const char*)Bs[buf] + row * 128 + slot);
      }
      __builtin_amdgcn_s_setprio(1);
#pragma unroll
      for (int mt = 0; mt < 8; ++mt)
#pragma unroll
        for (int nt = 0; nt < 4; ++nt)
          acc[mt][nt] = __builtin_amdgcn_mfma_f32_16x16x32_bf16(bfv[nt], af[mt], acc[mt][nt], 0, 0, 0);
      __builtin_amdgcn_s_setprio(0);
    }
    asm volatile("" ::: "memory");
    __builtin_amdgcn_s_barrier();
    buf ^= 1;
  }

#pragma unroll
  for (int mt = 0; mt < 8; ++mt) {
    const int gr = m0 + wm * 128 + mt * 16 + rA;
    float* rowp = pr.outp + (size_t)gr * 1024;
#pragma unroll
    for (int nt = 0; nt < 4; ++nt) {
      const int d0 = n0 + wn * 64 + nt * 16 + rG * 4;
      f32x4 o;
#pragma unroll
      for (int i = 0; i < 4; ++i) o[i] = acc[mt][nt][i] + pr.bo[d0 + i];
      *(f32x4*)(rowp + d0) = o;
    }
  }
}

// ---------------- 128x128 m97-style GEMM: combined-weight prep ----------------

__global__ __launch_bounds__(256) void k_wcomb(GP pr) {
  __shared__ __bf16 As[128 * 32];
  __shared__ __bf16 Bs[128 * 32];
  const int tid = threadIdx.x;
  const int wave = tid >> 6, lane = tid & 63;
  const int wm = wave >> 1, wn = wave & 1;
  const int nbn = pr.N >> 7;
  const int bm = blockIdx.x / nbn, bn = blockIdx.x - bm * nbn;
  const int m0 = bm << 7, n0 = bn << 7;
  const int K = pr.K;
  const int rA = lane & 15, rG = lane >> 4;

  f32x4 acc[4][4] = {};

  for (int k0 = 0; k0 < K; k0 += 32) {
#pragma unroll
    for (int ch = 0; ch < 2; ++ch) {
      const int fb = ch * 4096 + wave * 1024;
      const int e = (fb >> 1) + lane * 8;
      const int row = e >> 5, col = e & 31;
      gld16(pr.A  + (size_t)(m0 + row) * K + (k0 + col), (char*)As + fb);
      gld16(pr.Bt + (size_t)(n0 + row) * K + (k0 + col), (char*)Bs + fb);
    }
    __syncthreads();

    bf16x8 af[4], bfv[4];
#pragma unroll
    for (int mt = 0; mt < 4; ++mt)
      af[mt] = *(const bf16x8*)&As[(wm * 64 + mt * 16 + rA) * 32 + rG * 8];
#pragma unroll
    for (int nt = 0; nt < 4; ++nt)
      bfv[nt] = *(const bf16x8*)&Bs[(wn * 64 + nt * 16 + rA) * 32 + rG * 8];
#pragma unroll
    for (int mt = 0; mt < 4; ++mt)
#pragma unroll
      for (int nt = 0; nt < 4; ++nt)
        acc[mt][nt] = __builtin_amdgcn_mfma_f32_16x16x32_bf16(af[mt], bfv[nt], acc[mt][nt], 0, 0, 0);
    __syncthreads();
  }

#pragma unroll
  for (int mt = 0; mt < 4; ++mt) {
#pragma unroll
    for (int nt = 0; nt < 4; ++nt) {
      const int gc = n0 + wn * 64 + nt * 16 + rA;
      const int grb = m0 + wm * 64 + mt * 16 + rG * 4;
#pragma unroll
      for (int i = 0; i < 4; ++i)
        pr.qb[(size_t)(grb + i) * 1024 + gc] = (__bf16)acc[mt][nt][i];
    }
  }
}

// ---------------- deformable attention v6b: LDS K + flipped lanes + fast math ----------

#define ATILE 128
#define AROWS 266
#define ARST  72

__global__ __launch_bounds__(256) void k_attn6(
    const __bf16* __restrict__ qb, const __bf16* __restrict__ kb, const __bf16* __restrict__ vb,
    const float* __restrict__ offa, const float* __restrict__ psa,
    const float* __restrict__ elapsed,
    const float* __restrict__ dec, const float* __restrict__ pbias,
    __bf16* __restrict__ attn_out, F8 anchors) {
  __shared__ __align__(16) __bf16 lk[AROWS * ARST];
  __shared__ float lel[AROWS];

  const int bid = blockIdx.x;
  const int t0 = bid & 15, h = (bid >> 4) & 15, b = bid >> 8;
  const int s0 = t0 * ATILE;
  const int lo = (s0 > 136) ? (s0 - 136) : 0;
  const int tid = threadIdx.x;
  const size_t bBase = (size_t)b * S_LEN;
  const int hd0 = h * 64;

  for (int idx = tid; idx < AROWS * 8; idx += 256) {
    const int row = idx >> 3, c8 = idx & 7;
    int gr = lo + row; if (gr > S_LEN - 1) gr = S_LEN - 1;
    *(bf16x8*)(lk + row * ARST + c8 * 8) =
        *(const bf16x8*)(kb + (bBase + gr) * DIM + hd0 + c8 * 8);
  }
  for (int idx = tid; idx < AROWS; idx += 256) {
    int gr = lo + idx; if (gr > S_LEN - 1) gr = S_LEN - 1;
    lel[idx] = elapsed[b * S_LEN + gr];
  }
  __syncthreads();

  const int wv = tid >> 6, lane = tid & 63;
  const int p = lane & 7, c = lane >> 3;        // p in low bits
  const int pb0 = p & 1, pb1 = (p >> 1) & 1, pb2 = p >> 2;
  const float anchor = anchors.v[p];
  const int hp = h * NP + p;
  const float decv = dec[hp], pbv = pbias[hp];

  const int sw0 = s0 + wv * 32;
  const __bf16* vbase = vb + bBase * DIM + hd0 + c * 8;
  const __bf16* qbase = qb + bBase * DIM + hd0 + c * 8;
  size_t ppos0 = (((size_t)b * NH + h) * S_LEN + sw0) * NP + p;

#pragma unroll 2
  for (int i = 0; i < 32; ++i) {
    const int s = sw0 + i;
    const float off = offa[ppos0 + (size_t)i * NP];
    const float psv = psa[ppos0 + (size_t)i * NP];
    const bf16x8 qv = *(const bf16x8*)(qbase + (size_t)s * DIM);

    float pos = (float)s - anchor + off * 8.0f;
    pos = fminf(fmaxf(pos, 0.0f), (float)s);
    int li = (int)pos;
    const float alpha = pos - (float)li;
    int ri = li + 1; if (ri > S_LEN - 1) ri = S_LEN - 1;
    const int lr = li - lo, rr = ri - lo;

    const bf16x8 vl = *(const bf16x8*)(vbase + (size_t)li * DIM);
    const bf16x8 vr = *(const bf16x8*)(vbase + (size_t)ri * DIM);

    const bf16x8 kl = *(const bf16x8*)(lk + lr * ARST + c * 8);
    const bf16x8 kr = *(const bf16x8*)(lk + rr * ARST + c * 8);
    float dpl = 0.f, dpr = 0.f;
#pragma unroll
    for (int j = 0; j < 8; ++j) {
      dpl += (float)qv[j] * (float)kl[j];
      dpr += (float)qv[j] * (float)kr[j];
    }
    float dot = dpl + alpha * (dpr - dpl);
    dot += __shfl_xor(dot, 8);
    dot += __shfl_xor(dot, 16);
    dot += __shfl_xor(dot, 32);

    const float el_s = lel[s - lo];
    const float ell = lel[lr];
    const float elr2 = lel[rr];
    const float elsamp = ell + alpha * (elr2 - ell);
    const float relarg = fmaxf(el_s - elsamp, 0.f);
    const float rel = __logf(1.0f + relarg);
    const float score = dot * 0.125f + psv + pbv - decv * rel;

    const float e = __expf(score);
    float dsum = e;
    dsum += __shfl_xor(dsum, 1);
    dsum += __shfl_xor(dsum, 2);
    dsum += __shfl_xor(dsum, 4);
    const float wgt = e * __builtin_amdgcn_rcpf(dsum);
    const float wl = wgt * (1.0f - alpha), wr = wgt * alpha;

    float o[8];
#pragma unroll
    for (int j = 0; j < 8; ++j)
      o[j] = wl * (float)vl[j] + wr * (float)vr[j];

    float r00 = (pb0 ? o[1] : o[0]) + __shfl_xor(pb0 ? o[0] : o[1], 1);
    float r01 = (pb0 ? o[3] : o[2]) + __shfl_xor(pb0 ? o[2] : o[3], 1);
    float r02 = (pb0 ? o[5] : o[4]) + __shfl_xor(pb0 ? o[4] : o[5], 1);
    float r03 = (pb0 ? o[7] : o[6]) + __shfl_xor(pb0 ? o[6] : o[7], 1);
    float r10 = (pb1 ? r01 : r00) + __shfl_xor(pb1 ? r00 : r01, 2);
    float r11 = (pb1 ? r03 : r02) + __shfl_xor(pb1 ? r02 : r03, 2);
    float rf = (pb2 ? r11 : r10) + __shfl_xor(pb2 ? r10 : r11, 4);

    attn_out[(bBase + s) * DIM + hd0 + c * 8 + p] = (__bf16)rf;
  }
}

// ---------------- host ----------------

extern "C" void kernel_launch(void* const* d_in, const int* in_sizes, int n_in,
                              void* d_out, int out_size, void* d_ws, size_t ws_size,
                              hipStream_t stream) {
  const float* x    = (const float*)d_in[0];
  const float* td   = (const float*)d_in[1];
  const float* Wq   = (const float*)d_in[2];
  const float* bq   = (const float*)d_in[3];
  const float* Wk   = (const float*)d_in[4];
  const float* bk   = (const float*)d_in[5];
  const float* Wv   = (const float*)d_in[6];
  const float* bv   = (const float*)d_in[7];
  const float* Wc   = (const float*)d_in[8];
  const float* bc   = (const float*)d_in[9];
  const float* Eb   = (const float*)d_in[10];
  const float* Wt   = (const float*)d_in[11];
  const float* bt   = (const float*)d_in[12];
  const float* Woff = (const float*)d_in[13];
  const float* boff = (const float*)d_in[14];
  const float* Wps  = (const float*)d_in[15];
  const float* bps  = (const float*)d_in[16];
  const float* Wo   = (const float*)d_in[17];
  const float* bo   = (const float*)d_in[18];
  const float* pb   = (const float*)d_in[19];
  const float* tdw  = (const float*)d_in[20];
  const float* tdb  = (const float*)d_in[21];

  char* w = (char*)d_ws;
  size_t off = 0;
  auto take = [&](size_t n) {
    char* pp = w + off;
    off += (n + 255) & ~(size_t)255;
    return pp;
  };
  __bf16* xb    = (__bf16*)take(33554432);
  __bf16* wcat  = (__bf16*)take(8388608);
  __bf16* w2t   = (__bf16*)take(524288);
  __bf16* wot   = (__bf16*)take(2097152);
  __bf16* wt1b  = (__bf16*)take(2097152);
  __bf16* qb    = (__bf16*)take(33554432);
  __bf16* kb    = (__bf16*)take(33554432);
  __bf16* vb    = (__bf16*)take(33554432);
  float* offa   = (float*)take(8388608);
  float* psa    = (float*)take(8388608);
  float* elap   = (float*)take(65536);
  float* dl     = (float*)take(65536);
  int*   bucket = (int*)take(65536);
  float* wc_t   = (float*)take(4096);
  float* ebt    = (float*)take(36864);
  float* biasp  = (float*)take(4096);
  float* ebias  = (float*)take(12288);
  float* cw2    = (float*)take(1024);
  float* bo2    = (float*)take(1024);
  float* ebo    = (float*)take(9216);
  float* dec    = (float*)take(512);
  float* pbias  = (float*)take(512);
  if (off > ws_size) return;
  __bf16* attn_out = xb;  // alias: xb dead after G1

  F8 anc;
  {
    const double step = log2(129.0) / 7.0;
    anc.v[0] = 0.0f;
    for (int p = 1; p < 8; ++p) anc.v[p] = (float)(exp2((double)p * step) - 1.0);
  }

  k_cast2<<<17408, 256, 0, stream>>>(x, xb, Wt, wt1b);
  k_pack_all<<<dim3(256, 6), 256, 0, stream>>>(Wq, Wk, Wv, Wo, Woff, Wps, wcat, wot, w2t);
  k_prepC<<<13, 256, 0, stream>>>(bq, bk, bv, tdw, tdb, pb, ebias, dec, pbias);
  k_prepA<<<dim3(16, 10), 256, 0, stream>>>(Wc, bc, Eb, Wt, bt, wc_t, biasp, ebt);
  k_prepB<<<dim3(4, 11), 512, 0, stream>>>(wc_t, biasp, ebt, Woff, Wps, boff, bps, cw2, bo2, ebo);
  k_rowcum<<<8, 256, 0, stream>>>(td, dl, bucket, elap);

  GP gw = {};
  gw.A = w2t; gw.Bt = wt1b; gw.M = 256; gw.N = 1024; gw.K = 1024;
  gw.qb = wcat + 3145728;
  k_wcomb<<<16, 256, 0, stream>>>(gw);

  GP g1 = {};
  g1.A = xb; g1.Bt = wcat; g1.M = 16384; g1.N = 3328; g1.K = 1024;
  g1.qb = qb; g1.kb = kb; g1.vb = vb;
  g1.ebias = ebias; g1.cw2 = cw2; g1.ebo = ebo; g1.bo2 = bo2;
  g1.dl = dl; g1.bucket = bucket;
  g1.offa = offa; g1.psa = psa;
  k_g128b<0><<<128 * 26, 256, 0, stream>>>(g1);

  k_attn6<<<2048, 256, 0, stream>>>(qb, kb, vb, offa, psa, elap, dec, pbias, attn_out, anc);

  GP g3 = {};
  g3.A = attn_out; g3.Bt = wot; g3.M = 16384; g3.N = 1024; g3.K = 1024;
  g3.outp = (float*)d_out; g3.bo = bo;
  k_gemm2<2><<<64 * 4, 512, 0, stream>>>(g3);
}